// Round 2
// baseline (170.213 us; speedup 1.0000x reference)
//
#include <hip/hip_runtime.h>
#include <hip/hip_bf16.h>

#define NFEAT 9
#define VOCAB 119
#define HIDDEN 128
#define NHEAD 8
#define HDIM 16
#define KNBR 16

typedef __attribute__((ext_vector_type(8))) short short8;   // 8 bf16 = 4 VGPRs
typedef __attribute__((ext_vector_type(4))) float f32x4;    // MFMA C/D

// butterfly helper over 16-lane groups; offset must be an IMMEDIATE (template)
template <int OFFS>
__device__ __forceinline__ float swz_xor(float v) {
    int r = __builtin_amdgcn_ds_swizzle(__float_as_int(v), OFFS);
    return __int_as_float(r);
}

// ---------- sentinel fill (distinguishable failure signatures) ----------
__global__ void fill_kernel(float* out, int n, float val) {
    int i = blockIdx.x * blockDim.x + threadIdx.x;
    if (i < n) out[i] = val;
}

// ---------- Kernel 0: W -> W^T bf16 (one-time per launch, 12 blocks) ----------
__global__ __launch_bounds__(256) void wt_kernel(
    const float* __restrict__ Wq, const float* __restrict__ Wk,
    const float* __restrict__ Wv, short* __restrict__ Wt)
{
    int mat = blockIdx.x >> 2, tile = blockIdx.x & 3;  // 3 mats x 4 row-tiles
    const float* W = (mat == 0) ? Wq : (mat == 1) ? Wk : Wv;
    __shared__ float ls[32 * HIDDEN];
    int tid = threadIdx.x;
    int cc0 = tile * 32;
    #pragma unroll
    for (int j = 0; j < 16; ++j) {
        int idx = j * 256 + tid;
        ls[idx] = W[(size_t)cc0 * HIDDEN + idx];   // coalesced
    }
    __syncthreads();
    int c = tid & 127, hf = tid >> 7;  // thread: output row c, 16 cc's
    unsigned int ob[8];
    #pragma unroll
    for (int j = 0; j < 8; ++j) {
        int ccl = hf * 16 + 2 * j;
        __hip_bfloat16 b0 = __float2bfloat16(ls[ccl * HIDDEN + c]);
        __hip_bfloat16 b1 = __float2bfloat16(ls[(ccl + 1) * HIDDEN + c]);
        ob[j] = (unsigned int)*reinterpret_cast<unsigned short*>(&b0)
              | ((unsigned int)*reinterpret_cast<unsigned short*>(&b1) << 16);
    }
    unsigned int* dst = reinterpret_cast<unsigned int*>(
        Wt + (size_t)mat * HIDDEN * HIDDEN + (size_t)c * HIDDEN + cc0 + hf * 16);
    #pragma unroll
    for (int j = 0; j < 8; ++j) dst[j] = ob[j];
}

// ---------- Kernel 1: fused encoder + MFMA QKV (FROZEN from r14) ----------
#define MT 32
#define HBS 136  // padded bf16 row stride; 2-way LDS aliasing = free (m136)

__global__ __launch_bounds__(256, 3) void qkv_kernel(
    const int* __restrict__ X, const float* __restrict__ emb,
    const short* __restrict__ Wt,
    const float* __restrict__ bq, const float* __restrict__ bk,
    const float* __restrict__ bv,
    float* __restrict__ qf, __hip_bfloat16* __restrict__ kv, int N)
{
    __shared__ __align__(16) short hb[MT * HBS];
    __shared__ int xs[MT * NFEAT];

    const int tid = threadIdx.x;
    const int n0 = blockIdx.x * MT;

    for (int i = tid; i < MT * NFEAT; i += 256) {
        int n = n0 + i / NFEAT;
        int v = (n < N) ? X[(size_t)n * NFEAT + (i % NFEAT)] : 0;
        xs[i] = min(max(v, 0), VOCAB - 1);  // clamp: never fault
    }
    __syncthreads();

    {
        const int cg = tid & 31;        // 32 groups x 4 channels
        const int slot = tid >> 5;      // 8 slots x 4 nodes
        #pragma unroll
        for (int i = 0; i < 4; ++i) {
            int nl = slot * 4 + i;
            float4 acc = {0.f, 0.f, 0.f, 0.f};
            #pragma unroll
            for (int f = 0; f < NFEAT; ++f) {
                const float4 e = *reinterpret_cast<const float4*>(
                    &emb[((size_t)f * VOCAB + xs[nl * NFEAT + f]) * HIDDEN + cg * 4]);
                acc.x += e.x; acc.y += e.y; acc.z += e.z; acc.w += e.w;
            }
            __hip_bfloat162 p0 = __float22bfloat162_rn(make_float2(acc.x, acc.y));
            __hip_bfloat162 p1 = __float22bfloat162_rn(make_float2(acc.z, acc.w));
            uint2 u;
            u.x = *reinterpret_cast<unsigned int*>(&p0);
            u.y = *reinterpret_cast<unsigned int*>(&p1);
            *reinterpret_cast<uint2*>(&hb[nl * HBS + cg * 4]) = u;  // 8B aligned
        }
    }
    __syncthreads();  // hb ready

    const int wave = tid >> 6, lane = tid & 63;
    const int l15 = lane & 15, quad = lane >> 4;

    // B stationary: wave owns channel groups wave*2, wave*2+1 (once per block)
    short8 b[2][3][4];
    float bias[2][3];
    #pragma unroll
    for (int g = 0; g < 2; ++g) {
        const int n = (wave * 2 + g) * 16 + l15;   // output channel
        #pragma unroll
        for (int mat = 0; mat < 3; ++mat) {
            #pragma unroll
            for (int k0 = 0; k0 < 4; ++k0)
                b[g][mat][k0] = *reinterpret_cast<const short8*>(
                    &Wt[(size_t)mat * HIDDEN * HIDDEN + n * HIDDEN + k0 * 32 + quad * 8]);
            bias[g][mat] = (mat == 0) ? bq[n] : (mat == 1) ? bk[n] : bv[n];
        }
    }

    #pragma unroll
    for (int mt = 0; mt < 2; ++mt) {
        const int mloc = mt * 16 + l15;          // A row (node within block)
        short8 a[4];
        #pragma unroll
        for (int k0 = 0; k0 < 4; ++k0)           // A[m][k=k0*32+quad*8..+7]
            a[k0] = *reinterpret_cast<const short8*>(
                &hb[mloc * HBS + k0 * 32 + quad * 8]);
        #pragma unroll
        for (int g = 0; g < 2; ++g) {
            const int n = (wave * 2 + g) * 16 + l15;
            f32x4 acc[3] = {{0.f,0.f,0.f,0.f},{0.f,0.f,0.f,0.f},{0.f,0.f,0.f,0.f}};
            #pragma unroll
            for (int mat = 0; mat < 3; ++mat)
                #pragma unroll
                for (int k0 = 0; k0 < 4; ++k0)
                    acc[mat] = __builtin_amdgcn_mfma_f32_16x16x32_bf16(
                        a[k0], b[g][mat][k0], acc[mat], 0, 0, 0);
            #pragma unroll
            for (int mat = 0; mat < 3; ++mat) {
                #pragma unroll
                for (int r = 0; r < 4; ++r) {    // C row = quad*4+r (node in m-tile)
                    int node = n0 + mt * 16 + quad * 4 + r;
                    if (node < N) {
                        float val = acc[mat][r] + bias[g][mat];
                        if (mat == 0)      qf[(size_t)node * HIDDEN + n] = val * 0.25f;
                        else if (mat == 1) kv[(size_t)node * 256 + n] = __float2bfloat16(val);
                        else               kv[(size_t)node * 256 + 128 + n] = __float2bfloat16(val);
                    }
                }
            }
        }
    }
}

// ---------------- Kernel 2: ELL sparse attention (r18: barrier-free, all-direct) ----------------
// r17 profile: VALUBusy 73%, HBM 37%, 5.8M LDS-conflict cycles, 3 barriers each
// draining vmcnt(0) (so the "overlapped" v loads never actually overlapped).
// r18: (1) k read DIRECTLY global->regs: thread (hh,kk) needs exactly 32B of
// neighbor kk's k-half; lanes sharing kk coalesce to 128B. Mask skip preserved
// at identical granularity (masked row -> all 8 heads skip -> whole 256B).
// (2) idx/mask via broadcast int4/scalar global loads (L1-served) -> no idxl.
// (3) sl barrier removed: score lanes (t=hh*16+kk) and PV lanes (t=dim,
// head=t>>4) for the same head are IN THE SAME WAVE -> intra-wave ds_write->
// ds_read ordered by compiler lgkmcnt. Zero barriers; LDS 10240B -> 1280B;
// v loads issued last so they stay in flight across scores+softmax.
// Math bit-identical to r17.
#define NPB2 2

__global__ __launch_bounds__(256) void attn_kernel(
    const int* __restrict__ nbr_idx, const int* __restrict__ nbr_mask,
    const float* __restrict__ qf, const __hip_bfloat16* __restrict__ kv,
    float* __restrict__ out, int N)
{
    __shared__ __align__(16) float sl[NPB2][NHEAD][20];  // [head][16 w + pad]

    const int tid = threadIdx.x;
    const int local = tid >> 7; // node within block
    const int t = tid & 127;    // thread within node
    int n = blockIdx.x * NPB2 + local;
    if (n >= N) n = N - 1;  // duplicate work (identical bits), barrier-free safe

    const int hh = t >> 4;   // head (0..7)
    const int kk = t & 15;   // neighbor (scores) / dim (PV)

    // idx -> regs: 4x int4 broadcast loads (same 64B per node, L1-served)
    int idxr[KNBR];
    {
        const int4* ip = reinterpret_cast<const int4*>(nbr_idx + (size_t)n * KNBR);
        #pragma unroll
        for (int m4 = 0; m4 < 4; ++m4) {
            int4 iv = ip[m4];
            idxr[4 * m4 + 0] = min(max(iv.x, 0), N - 1);
            idxr[4 * m4 + 1] = min(max(iv.y, 0), N - 1);
            idxr[4 * m4 + 2] = min(max(iv.z, 0), N - 1);
            idxr[4 * m4 + 3] = min(max(iv.w, 0), N - 1);
        }
    }
    const int mymsk = nbr_mask[(size_t)n * KNBR + kk];

    // k direct global->regs: 32B of neighbor kk's k-half, head hh (exec-masked)
    short8 k0 = {0, 0, 0, 0, 0, 0, 0, 0};
    short8 k1 = {0, 0, 0, 0, 0, 0, 0, 0};
    if (mymsk) {
        const short8* kp = reinterpret_cast<const short8*>(
            (const short*)kv + (size_t)idxr[kk] * 256 + hh * HDIM);
        k0 = kp[0];
        k1 = kp[1];
    }

    // q -> regs (16-lane broadcast per head, L1-served)
    float qr[HDIM];
    {
        const float4* qp = reinterpret_cast<const float4*>(
            qf + (size_t)n * HIDDEN + hh * HDIM);
        #pragma unroll
        for (int c4 = 0; c4 < 4; ++c4) {
            float4 qv = qp[c4];
            qr[4 * c4 + 0] = qv.x; qr[4 * c4 + 1] = qv.y;
            qr[4 * c4 + 2] = qv.z; qr[4 * c4 + 3] = qv.w;
        }
    }

    // v direct global->regs: per j the 128 node-threads read 256B contiguous.
    // Issued LAST so these 16 loads stay in flight across scores+softmax
    // (no barrier = no vmcnt(0) drain until PV actually consumes them).
    float vr[KNBR];
    #pragma unroll
    for (int j = 0; j < KNBR; ++j) {
        unsigned int u = *((const unsigned short*)kv + (size_t)idxr[j] * 256 + 128 + t);
        vr[j] = __uint_as_float(u << 16);
    }

    // scores + butterfly softmax: thread (hh, kk); kk = low 4 lane bits
    {
        const __hip_bfloat162* kp0 = reinterpret_cast<const __hip_bfloat162*>(&k0);
        const __hip_bfloat162* kp1 = reinterpret_cast<const __hip_bfloat162*>(&k1);
        float s = 0.f;
        #pragma unroll
        for (int d2 = 0; d2 < 4; ++d2) {
            float2 f0 = __bfloat1622float2(kp0[d2]);
            float2 f1 = __bfloat1622float2(kp1[d2]);
            s += qr[2 * d2] * f0.x + qr[2 * d2 + 1] * f0.y;
            s += qr[8 + 2 * d2] * f1.x + qr[8 + 2 * d2 + 1] * f1.y;
        }
        if (!mymsk) s = -1e9f;       // masked rows (k regs zero) discarded here
        float m = s;
        m = fmaxf(m, swz_xor<0x041F>(m));
        m = fmaxf(m, swz_xor<0x081F>(m));
        m = fmaxf(m, swz_xor<0x101F>(m));
        m = fmaxf(m, swz_xor<0x201F>(m));
        float e = __expf(s - m);
        float d = e;
        d += swz_xor<0x041F>(d);
        d += swz_xor<0x081F>(d);
        d += swz_xor<0x101F>(d);
        d += swz_xor<0x201F>(d);
        sl[local][hh][kk] = e / d;   // final weight; all-masked -> 1/16 exact
    }
    // NO barrier: producer lanes (head hh) and consumer lanes (dims of head hh)
    // are in the same wave; compiler-inserted lgkmcnt orders ds_write->ds_read.

    // PV: w via 4x b128 broadcast; v already in regs -> pure FMA
    {
        float o = 0.f;
        const float4* wp = reinterpret_cast<const float4*>(&sl[local][t >> 4][0]);
        #pragma unroll
        for (int m4 = 0; m4 < 4; ++m4) {
            float4 w4 = wp[m4];
            o += w4.x * vr[4 * m4 + 0] + w4.y * vr[4 * m4 + 1]
               + w4.z * vr[4 * m4 + 2] + w4.w * vr[4 * m4 + 3];
        }
        out[(size_t)n * HIDDEN + t] = o;  // OUTPUT IS FLOAT32 (verified r6)
    }
}

extern "C" void kernel_launch(void* const* d_in, const int* in_sizes, int n_in,
                              void* d_out, int out_size, void* d_ws, size_t ws_size,
                              hipStream_t stream)
{
    float* out = (float*)d_out;

    bool ok = (n_in == 10);
    int N = ok ? in_sizes[0] / NFEAT : 0;
    ok = ok && N > 0 && in_sizes[0] == N * NFEAT
            && in_sizes[1] == N * KNBR
            && in_sizes[2] == N * KNBR
            && in_sizes[3] == NFEAT * VOCAB * HIDDEN
            && in_sizes[4] == HIDDEN * HIDDEN && in_sizes[5] == HIDDEN
            && in_sizes[6] == HIDDEN * HIDDEN && in_sizes[7] == HIDDEN
            && in_sizes[8] == HIDDEN * HIDDEN && in_sizes[9] == HIDDEN
            && out_size == N * HIDDEN;
    if (!ok) {
        fill_kernel<<<(out_size + 255) / 256, 256, 0, stream>>>(out, out_size, 0.0f);
        return;
    }
    size_t need = (size_t)N * 1024 + 3 * HIDDEN * HIDDEN * sizeof(short);
    if (ws_size < need) {
        fill_kernel<<<(out_size + 255) / 256, 256, 0, stream>>>(out, out_size, 1.0f);
        return;
    }

    const int* X        = (const int*)d_in[0];
    const int* nbr_idx  = (const int*)d_in[1];
    const int* nbr_mask = (const int*)d_in[2];
    const float* emb = (const float*)d_in[3];
    const float* Wq  = (const float*)d_in[4];
    const float* bq  = (const float*)d_in[5];
    const float* Wk  = (const float*)d_in[6];
    const float* bk  = (const float*)d_in[7];
    const float* Wv  = (const float*)d_in[8];
    const float* bv  = (const float*)d_in[9];

    // workspace: qf fp32 [N][128] | kv bf16 [N][256] | Wt bf16 [3][128][128]
    float* qf = (float*)d_ws;
    __hip_bfloat16* kv =
        (__hip_bfloat16*)((char*)d_ws + (size_t)N * HIDDEN * sizeof(float));
    short* Wt = (short*)((char*)d_ws + (size_t)N * 1024);

    wt_kernel<<<12, 256, 0, stream>>>(Wq, Wk, Wv, Wt);
    qkv_kernel<<<(N + MT - 1) / MT, 256, 0, stream>>>(
        X, emb, Wt, bq, bk, bv, qf, kv, N);
    attn_kernel<<<(N + NPB2 - 1) / NPB2, 256, 0, stream>>>(
        nbr_idx, nbr_mask, qf, kv, out, N);
}

// Round 3
// 165.920 us; speedup vs baseline: 1.0259x; 1.0259x over previous
//
#include <hip/hip_runtime.h>
#include <hip/hip_bf16.h>

#define NFEAT 9
#define VOCAB 119
#define HIDDEN 128
#define NHEAD 8
#define HDIM 16
#define KNBR 16

typedef __attribute__((ext_vector_type(8))) short short8;   // 8 bf16 = 4 VGPRs
typedef __attribute__((ext_vector_type(4))) float f32x4;    // MFMA C/D

// butterfly helper over 16-lane groups; offset must be an IMMEDIATE (template)
template <int OFFS>
__device__ __forceinline__ float swz_xor(float v) {
    int r = __builtin_amdgcn_ds_swizzle(__float_as_int(v), OFFS);
    return __int_as_float(r);
}

// ---------- sentinel fill (distinguishable failure signatures) ----------
__global__ void fill_kernel(float* out, int n, float val) {
    int i = blockIdx.x * blockDim.x + threadIdx.x;
    if (i < n) out[i] = val;
}

// ---------- Kernel 0: W -> W^T bf16 (one-time per launch, 12 blocks) ----------
__global__ __launch_bounds__(256) void wt_kernel(
    const float* __restrict__ Wq, const float* __restrict__ Wk,
    const float* __restrict__ Wv, short* __restrict__ Wt)
{
    int mat = blockIdx.x >> 2, tile = blockIdx.x & 3;  // 3 mats x 4 row-tiles
    const float* W = (mat == 0) ? Wq : (mat == 1) ? Wk : Wv;
    __shared__ float ls[32 * HIDDEN];
    int tid = threadIdx.x;
    int cc0 = tile * 32;
    #pragma unroll
    for (int j = 0; j < 16; ++j) {
        int idx = j * 256 + tid;
        ls[idx] = W[(size_t)cc0 * HIDDEN + idx];   // coalesced
    }
    __syncthreads();
    int c = tid & 127, hf = tid >> 7;  // thread: output row c, 16 cc's
    unsigned int ob[8];
    #pragma unroll
    for (int j = 0; j < 8; ++j) {
        int ccl = hf * 16 + 2 * j;
        __hip_bfloat16 b0 = __float2bfloat16(ls[ccl * HIDDEN + c]);
        __hip_bfloat16 b1 = __float2bfloat16(ls[(ccl + 1) * HIDDEN + c]);
        ob[j] = (unsigned int)*reinterpret_cast<unsigned short*>(&b0)
              | ((unsigned int)*reinterpret_cast<unsigned short*>(&b1) << 16);
    }
    unsigned int* dst = reinterpret_cast<unsigned int*>(
        Wt + (size_t)mat * HIDDEN * HIDDEN + (size_t)c * HIDDEN + cc0 + hf * 16);
    #pragma unroll
    for (int j = 0; j < 8; ++j) dst[j] = ob[j];
}

// ---------- Kernel 1: fused encoder + MFMA QKV (FROZEN from r14) ----------
#define MT 32
#define HBS 136  // padded bf16 row stride; 2-way LDS aliasing = free (m136)

__global__ __launch_bounds__(256, 3) void qkv_kernel(
    const int* __restrict__ X, const float* __restrict__ emb,
    const short* __restrict__ Wt,
    const float* __restrict__ bq, const float* __restrict__ bk,
    const float* __restrict__ bv,
    float* __restrict__ qf, __hip_bfloat16* __restrict__ kv, int N)
{
    __shared__ __align__(16) short hb[MT * HBS];
    __shared__ int xs[MT * NFEAT];

    const int tid = threadIdx.x;
    const int n0 = blockIdx.x * MT;

    for (int i = tid; i < MT * NFEAT; i += 256) {
        int n = n0 + i / NFEAT;
        int v = (n < N) ? X[(size_t)n * NFEAT + (i % NFEAT)] : 0;
        xs[i] = min(max(v, 0), VOCAB - 1);  // clamp: never fault
    }
    __syncthreads();

    {
        const int cg = tid & 31;        // 32 groups x 4 channels
        const int slot = tid >> 5;      // 8 slots x 4 nodes
        #pragma unroll
        for (int i = 0; i < 4; ++i) {
            int nl = slot * 4 + i;
            float4 acc = {0.f, 0.f, 0.f, 0.f};
            #pragma unroll
            for (int f = 0; f < NFEAT; ++f) {
                const float4 e = *reinterpret_cast<const float4*>(
                    &emb[((size_t)f * VOCAB + xs[nl * NFEAT + f]) * HIDDEN + cg * 4]);
                acc.x += e.x; acc.y += e.y; acc.z += e.z; acc.w += e.w;
            }
            __hip_bfloat162 p0 = __float22bfloat162_rn(make_float2(acc.x, acc.y));
            __hip_bfloat162 p1 = __float22bfloat162_rn(make_float2(acc.z, acc.w));
            uint2 u;
            u.x = *reinterpret_cast<unsigned int*>(&p0);
            u.y = *reinterpret_cast<unsigned int*>(&p1);
            *reinterpret_cast<uint2*>(&hb[nl * HBS + cg * 4]) = u;  // 8B aligned
        }
    }
    __syncthreads();  // hb ready

    const int wave = tid >> 6, lane = tid & 63;
    const int l15 = lane & 15, quad = lane >> 4;

    // B stationary: wave owns channel groups wave*2, wave*2+1 (once per block)
    short8 b[2][3][4];
    float bias[2][3];
    #pragma unroll
    for (int g = 0; g < 2; ++g) {
        const int n = (wave * 2 + g) * 16 + l15;   // output channel
        #pragma unroll
        for (int mat = 0; mat < 3; ++mat) {
            #pragma unroll
            for (int k0 = 0; k0 < 4; ++k0)
                b[g][mat][k0] = *reinterpret_cast<const short8*>(
                    &Wt[(size_t)mat * HIDDEN * HIDDEN + n * HIDDEN + k0 * 32 + quad * 8]);
            bias[g][mat] = (mat == 0) ? bq[n] : (mat == 1) ? bk[n] : bv[n];
        }
    }

    #pragma unroll
    for (int mt = 0; mt < 2; ++mt) {
        const int mloc = mt * 16 + l15;          // A row (node within block)
        short8 a[4];
        #pragma unroll
        for (int k0 = 0; k0 < 4; ++k0)           // A[m][k=k0*32+quad*8..+7]
            a[k0] = *reinterpret_cast<const short8*>(
                &hb[mloc * HBS + k0 * 32 + quad * 8]);
        #pragma unroll
        for (int g = 0; g < 2; ++g) {
            const int n = (wave * 2 + g) * 16 + l15;
            f32x4 acc[3] = {{0.f,0.f,0.f,0.f},{0.f,0.f,0.f,0.f},{0.f,0.f,0.f,0.f}};
            #pragma unroll
            for (int mat = 0; mat < 3; ++mat)
                #pragma unroll
                for (int k0 = 0; k0 < 4; ++k0)
                    acc[mat] = __builtin_amdgcn_mfma_f32_16x16x32_bf16(
                        a[k0], b[g][mat][k0], acc[mat], 0, 0, 0);
            #pragma unroll
            for (int mat = 0; mat < 3; ++mat) {
                #pragma unroll
                for (int r = 0; r < 4; ++r) {    // C row = quad*4+r (node in m-tile)
                    int node = n0 + mt * 16 + quad * 4 + r;
                    if (node < N) {
                        float val = acc[mat][r] + bias[g][mat];
                        if (mat == 0)      qf[(size_t)node * HIDDEN + n] = val * 0.25f;
                        else if (mat == 1) kv[(size_t)node * 256 + n] = __float2bfloat16(val);
                        else               kv[(size_t)node * 256 + 128 + n] = __float2bfloat16(val);
                    }
                }
            }
        }
    }
}

// ---------------- Kernel 2: ELL sparse attention (r19: VALU diet) ----------------
// r18 post-mortem: removing LDS staging + all barriers cut bank conflicts 29x
// and LDS 10240->1536B but dur ROSE 56->60us; VALUBusy pinned ~74% both ways
// => kernel is VALU-ISSUE-bound (~136 VALU insts/thread measured vs ~32 useful
// FMA). r19 cuts dead VALU ops, structure unchanged:
//  (1) idx clamp: min+max -> single unsigned min (neg wraps huge).  -16 ops
//  (2) all gather addrs as 32-bit unsigned BYTE offsets from uniform SGPR base
//      (N*512B < 2^32) -> SADDR+voffset form, 1 v_lshl_add_u32 per addr. -20
//  (3) e/d -> e * v_rcp_f32 (softmax weight err ~1e-7, absmax is bf16-bound)
//  (4) score/PV accumulation as even/odd paired chains (v_pk_fma-friendly)
#define NPB2 2

__global__ __launch_bounds__(256) void attn_kernel(
    const int* __restrict__ nbr_idx, const int* __restrict__ nbr_mask,
    const float* __restrict__ qf, const __hip_bfloat16* __restrict__ kv,
    float* __restrict__ out, int N)
{
    __shared__ __align__(16) float sl[NPB2][NHEAD][20];  // [head][16 w + pad]

    const int tid = threadIdx.x;
    const int local = tid >> 7; // node within block
    const int t = tid & 127;    // thread within node
    int n = blockIdx.x * NPB2 + local;
    if (n >= N) n = N - 1;  // duplicate work (identical bits), barrier-free safe

    const int hh = t >> 4;   // head (0..7)
    const int kk = t & 15;   // neighbor (scores) / dim (PV)

    const char* kvb = (const char*)kv;
    const unsigned nm1 = (unsigned)(N - 1);

    // idx -> regs: 4x int4 broadcast loads; clamp = single unsigned min
    int idxr[KNBR];
    {
        const int4* ip = reinterpret_cast<const int4*>(nbr_idx + (size_t)n * KNBR);
        #pragma unroll
        for (int m4 = 0; m4 < 4; ++m4) {
            int4 iv = ip[m4];
            idxr[4 * m4 + 0] = (int)min((unsigned)iv.x, nm1);
            idxr[4 * m4 + 1] = (int)min((unsigned)iv.y, nm1);
            idxr[4 * m4 + 2] = (int)min((unsigned)iv.z, nm1);
            idxr[4 * m4 + 3] = (int)min((unsigned)iv.w, nm1);
        }
    }
    const int mymsk = nbr_mask[(size_t)n * KNBR + kk];

    // k direct global->regs: 32B of neighbor kk's k-half, head hh (exec-masked;
    // whole-wave mask is NOT uniform here, but ~50% lanes skip = BW saved)
    short8 k0 = {0, 0, 0, 0, 0, 0, 0, 0};
    short8 k1 = {0, 0, 0, 0, 0, 0, 0, 0};
    if (mymsk) {
        // byte off = idx*512 + hh*32;  (t&0x70)<<1 == hh*32
        unsigned ko = ((unsigned)idxr[kk] << 9) + (((unsigned)t & 0x70u) << 1);
        k0 = *reinterpret_cast<const short8*>(kvb + ko);
        k1 = *reinterpret_cast<const short8*>(kvb + ko + 16);
    }

    // q -> regs (16-lane broadcast per head, L1-served)
    float qr[HDIM];
    {
        const float4* qp = reinterpret_cast<const float4*>(
            (const char*)qf + (((unsigned)n << 9) + ((unsigned)hh << 6)));
        #pragma unroll
        for (int c4 = 0; c4 < 4; ++c4) {
            float4 qv = qp[c4];
            qr[4 * c4 + 0] = qv.x; qr[4 * c4 + 1] = qv.y;
            qr[4 * c4 + 2] = qv.z; qr[4 * c4 + 3] = qv.w;
        }
    }

    // v direct global->regs: per j the 128 node-threads read 256B contiguous.
    // Issued last; stays in flight across scores+softmax (no barrier drain).
    // addr = SGPR base + 32-bit voffset (1 v_lshl_add_u32 each)
    float vr[KNBR];
    {
        const unsigned vbo = 256u + 2u * (unsigned)t;
        #pragma unroll
        for (int j = 0; j < KNBR; ++j) {
            unsigned u = *reinterpret_cast<const unsigned short*>(
                kvb + ((((unsigned)idxr[j]) << 9) + vbo));
            vr[j] = __uint_as_float(u << 16);
        }
    }

    // scores + butterfly softmax: thread (hh, kk); kk = low 4 lane bits
    {
        const __hip_bfloat162* kp0 = reinterpret_cast<const __hip_bfloat162*>(&k0);
        const __hip_bfloat162* kp1 = reinterpret_cast<const __hip_bfloat162*>(&k1);
        float ax = 0.f, ay = 0.f;   // even/odd paired chains (pk_fma-friendly)
        #pragma unroll
        for (int d2 = 0; d2 < 4; ++d2) {
            float2 f0 = __bfloat1622float2(kp0[d2]);
            float2 f1 = __bfloat1622float2(kp1[d2]);
            ax = fmaf(qr[2 * d2],     f0.x, ax);
            ay = fmaf(qr[2 * d2 + 1], f0.y, ay);
            ax = fmaf(qr[8 + 2 * d2],     f1.x, ax);
            ay = fmaf(qr[8 + 2 * d2 + 1], f1.y, ay);
        }
        float s = ax + ay;
        if (!mymsk) s = -1e9f;       // masked rows (k regs zero) discarded here
        float m = s;
        m = fmaxf(m, swz_xor<0x041F>(m));
        m = fmaxf(m, swz_xor<0x081F>(m));
        m = fmaxf(m, swz_xor<0x101F>(m));
        m = fmaxf(m, swz_xor<0x201F>(m));
        float e = __expf(s - m);
        float d = e;
        d += swz_xor<0x041F>(d);
        d += swz_xor<0x081F>(d);
        d += swz_xor<0x101F>(d);
        d += swz_xor<0x201F>(d);
        sl[local][hh][kk] = e * __builtin_amdgcn_rcpf(d);  // all-masked -> 1/16
    }
    // NO barrier: producer lanes (head hh) and consumer lanes (dims of head hh)
    // are in the same wave; compiler-inserted lgkmcnt orders ds_write->ds_read.

    // PV: w via 4x b128 broadcast; v already in regs -> paired FMA chains
    {
        float ox = 0.f, oy = 0.f;
        const float4* wp = reinterpret_cast<const float4*>(&sl[local][t >> 4][0]);
        #pragma unroll
        for (int m4 = 0; m4 < 4; ++m4) {
            float4 w4 = wp[m4];
            ox = fmaf(w4.x, vr[4 * m4 + 0], ox);
            oy = fmaf(w4.y, vr[4 * m4 + 1], oy);
            ox = fmaf(w4.z, vr[4 * m4 + 2], ox);
            oy = fmaf(w4.w, vr[4 * m4 + 3], oy);
        }
        float* op = reinterpret_cast<float*>(
            (char*)out + (((unsigned)n << 9) + 4u * (unsigned)t));
        *op = ox + oy;  // OUTPUT IS FLOAT32 (verified r6)
    }
}

extern "C" void kernel_launch(void* const* d_in, const int* in_sizes, int n_in,
                              void* d_out, int out_size, void* d_ws, size_t ws_size,
                              hipStream_t stream)
{
    float* out = (float*)d_out;

    bool ok = (n_in == 10);
    int N = ok ? in_sizes[0] / NFEAT : 0;
    ok = ok && N > 0 && in_sizes[0] == N * NFEAT
            && in_sizes[1] == N * KNBR
            && in_sizes[2] == N * KNBR
            && in_sizes[3] == NFEAT * VOCAB * HIDDEN
            && in_sizes[4] == HIDDEN * HIDDEN && in_sizes[5] == HIDDEN
            && in_sizes[6] == HIDDEN * HIDDEN && in_sizes[7] == HIDDEN
            && in_sizes[8] == HIDDEN * HIDDEN && in_sizes[9] == HIDDEN
            && out_size == N * HIDDEN;
    if (!ok) {
        fill_kernel<<<(out_size + 255) / 256, 256, 0, stream>>>(out, out_size, 0.0f);
        return;
    }
    size_t need = (size_t)N * 1024 + 3 * HIDDEN * HIDDEN * sizeof(short);
    if (ws_size < need) {
        fill_kernel<<<(out_size + 255) / 256, 256, 0, stream>>>(out, out_size, 1.0f);
        return;
    }

    const int* X        = (const int*)d_in[0];
    const int* nbr_idx  = (const int*)d_in[1];
    const int* nbr_mask = (const int*)d_in[2];
    const float* emb = (const float*)d_in[3];
    const float* Wq  = (const float*)d_in[4];
    const float* bq  = (const float*)d_in[5];
    const float* Wk  = (const float*)d_in[6];
    const float* bk  = (const float*)d_in[7];
    const float* Wv  = (const float*)d_in[8];
    const float* bv  = (const float*)d_in[9];

    // workspace: qf fp32 [N][128] | kv bf16 [N][256] | Wt bf16 [3][128][128]
    float* qf = (float*)d_ws;
    __hip_bfloat16* kv =
        (__hip_bfloat16*)((char*)d_ws + (size_t)N * HIDDEN * sizeof(float));
    short* Wt = (short*)((char*)d_ws + (size_t)N * 1024);

    wt_kernel<<<12, 256, 0, stream>>>(Wq, Wk, Wv, Wt);
    qkv_kernel<<<(N + MT - 1) / MT, 256, 0, stream>>>(
        X, emb, Wt, bq, bk, bv, qf, kv, N);
    attn_kernel<<<(N + NPB2 - 1) / NPB2, 256, 0, stream>>>(
        nbr_idx, nbr_mask, qf, kv, out, N);
}

// Round 4
// 165.827 us; speedup vs baseline: 1.0264x; 1.0006x over previous
//
#include <hip/hip_runtime.h>
#include <hip/hip_bf16.h>

#define NFEAT 9
#define VOCAB 119
#define HIDDEN 128
#define NHEAD 8
#define HDIM 16
#define KNBR 16

typedef __attribute__((ext_vector_type(8))) short short8;   // 8 bf16 = 4 VGPRs
typedef __attribute__((ext_vector_type(4))) float f32x4;    // MFMA C/D

// DPP rotate within 16-lane row: CTRL = 0x120|n -> row_ror:n (pure VALU, no LDS pipe)
template <int CTRL>
__device__ __forceinline__ float dpp_ror(float v) {
    return __int_as_float(__builtin_amdgcn_update_dpp(
        0, __float_as_int(v), CTRL, 0xF, 0xF, false));
}

// ---------- sentinel fill (distinguishable failure signatures) ----------
__global__ void fill_kernel(float* out, int n, float val) {
    int i = blockIdx.x * blockDim.x + threadIdx.x;
    if (i < n) out[i] = val;
}

// ---------- Kernel 0: W -> W^T bf16 (one-time per launch, 12 blocks) ----------
__global__ __launch_bounds__(256) void wt_kernel(
    const float* __restrict__ Wq, const float* __restrict__ Wk,
    const float* __restrict__ Wv, short* __restrict__ Wt)
{
    int mat = blockIdx.x >> 2, tile = blockIdx.x & 3;  // 3 mats x 4 row-tiles
    const float* W = (mat == 0) ? Wq : (mat == 1) ? Wk : Wv;
    __shared__ float ls[32 * HIDDEN];
    int tid = threadIdx.x;
    int cc0 = tile * 32;
    #pragma unroll
    for (int j = 0; j < 16; ++j) {
        int idx = j * 256 + tid;
        ls[idx] = W[(size_t)cc0 * HIDDEN + idx];   // coalesced
    }
    __syncthreads();
    int c = tid & 127, hf = tid >> 7;  // thread: output row c, 16 cc's
    unsigned int ob[8];
    #pragma unroll
    for (int j = 0; j < 8; ++j) {
        int ccl = hf * 16 + 2 * j;
        __hip_bfloat16 b0 = __float2bfloat16(ls[ccl * HIDDEN + c]);
        __hip_bfloat16 b1 = __float2bfloat16(ls[(ccl + 1) * HIDDEN + c]);
        ob[j] = (unsigned int)*reinterpret_cast<unsigned short*>(&b0)
              | ((unsigned int)*reinterpret_cast<unsigned short*>(&b1) << 16);
    }
    unsigned int* dst = reinterpret_cast<unsigned int*>(
        Wt + (size_t)mat * HIDDEN * HIDDEN + (size_t)c * HIDDEN + cc0 + hf * 16);
    #pragma unroll
    for (int j = 0; j < 8; ++j) dst[j] = ob[j];
}

// ---------- Kernel 1: fused encoder + MFMA QKV (FROZEN from r14) ----------
#define MT 32
#define HBS 136  // padded bf16 row stride; 2-way LDS aliasing = free (m136)

__global__ __launch_bounds__(256, 3) void qkv_kernel(
    const int* __restrict__ X, const float* __restrict__ emb,
    const short* __restrict__ Wt,
    const float* __restrict__ bq, const float* __restrict__ bk,
    const float* __restrict__ bv,
    float* __restrict__ qf, __hip_bfloat16* __restrict__ kv, int N)
{
    __shared__ __align__(16) short hb[MT * HBS];
    __shared__ int xs[MT * NFEAT];

    const int tid = threadIdx.x;
    const int n0 = blockIdx.x * MT;

    for (int i = tid; i < MT * NFEAT; i += 256) {
        int n = n0 + i / NFEAT;
        int v = (n < N) ? X[(size_t)n * NFEAT + (i % NFEAT)] : 0;
        xs[i] = min(max(v, 0), VOCAB - 1);  // clamp: never fault
    }
    __syncthreads();

    {
        const int cg = tid & 31;        // 32 groups x 4 channels
        const int slot = tid >> 5;      // 8 slots x 4 nodes
        #pragma unroll
        for (int i = 0; i < 4; ++i) {
            int nl = slot * 4 + i;
            float4 acc = {0.f, 0.f, 0.f, 0.f};
            #pragma unroll
            for (int f = 0; f < NFEAT; ++f) {
                const float4 e = *reinterpret_cast<const float4*>(
                    &emb[((size_t)f * VOCAB + xs[nl * NFEAT + f]) * HIDDEN + cg * 4]);
                acc.x += e.x; acc.y += e.y; acc.z += e.z; acc.w += e.w;
            }
            __hip_bfloat162 p0 = __float22bfloat162_rn(make_float2(acc.x, acc.y));
            __hip_bfloat162 p1 = __float22bfloat162_rn(make_float2(acc.z, acc.w));
            uint2 u;
            u.x = *reinterpret_cast<unsigned int*>(&p0);
            u.y = *reinterpret_cast<unsigned int*>(&p1);
            *reinterpret_cast<uint2*>(&hb[nl * HBS + cg * 4]) = u;  // 8B aligned
        }
    }
    __syncthreads();  // hb ready

    const int wave = tid >> 6, lane = tid & 63;
    const int l15 = lane & 15, quad = lane >> 4;

    // B stationary: wave owns channel groups wave*2, wave*2+1 (once per block)
    short8 b[2][3][4];
    float bias[2][3];
    #pragma unroll
    for (int g = 0; g < 2; ++g) {
        const int n = (wave * 2 + g) * 16 + l15;   // output channel
        #pragma unroll
        for (int mat = 0; mat < 3; ++mat) {
            #pragma unroll
            for (int k0 = 0; k0 < 4; ++k0)
                b[g][mat][k0] = *reinterpret_cast<const short8*>(
                    &Wt[(size_t)mat * HIDDEN * HIDDEN + n * HIDDEN + k0 * 32 + quad * 8]);
            bias[g][mat] = (mat == 0) ? bq[n] : (mat == 1) ? bk[n] : bv[n];
        }
    }

    #pragma unroll
    for (int mt = 0; mt < 2; ++mt) {
        const int mloc = mt * 16 + l15;          // A row (node within block)
        short8 a[4];
        #pragma unroll
        for (int k0 = 0; k0 < 4; ++k0)           // A[m][k=k0*32+quad*8..+7]
            a[k0] = *reinterpret_cast<const short8*>(
                &hb[mloc * HBS + k0 * 32 + quad * 8]);
        #pragma unroll
        for (int g = 0; g < 2; ++g) {
            const int n = (wave * 2 + g) * 16 + l15;
            f32x4 acc[3] = {{0.f,0.f,0.f,0.f},{0.f,0.f,0.f,0.f},{0.f,0.f,0.f,0.f}};
            #pragma unroll
            for (int mat = 0; mat < 3; ++mat)
                #pragma unroll
                for (int k0 = 0; k0 < 4; ++k0)
                    acc[mat] = __builtin_amdgcn_mfma_f32_16x16x32_bf16(
                        a[k0], b[g][mat][k0], acc[mat], 0, 0, 0);
            #pragma unroll
            for (int mat = 0; mat < 3; ++mat) {
                #pragma unroll
                for (int r = 0; r < 4; ++r) {    // C row = quad*4+r (node in m-tile)
                    int node = n0 + mt * 16 + quad * 4 + r;
                    if (node < N) {
                        float val = acc[mat][r] + bias[g][mat];
                        if (mat == 0)      qf[(size_t)node * HIDDEN + n] = val * 0.25f;
                        else if (mat == 1) kv[(size_t)node * 256 + n] = __float2bfloat16(val);
                        else               kv[(size_t)node * 256 + 128 + n] = __float2bfloat16(val);
                    }
                }
            }
        }
    }
}

// ---------------- Kernel 2: ELL sparse attention (r20: DPP softmax) ----------------
// r19 post-mortem: VALU diet cut VALUBusy 74->45% but dur only 60->55us =>
// LATENCY-bound. Longest serial chain: softmax butterfly = 8 sequential
// ds_swizzle round-trips x ~120cyc LDS latency ~= 1000 cyc/wave. r20 replaces
// ds_swizzle with DPP row_ror rotate-reduce (16-lane rows = exactly our
// (head,kk) groups): same inst count, serial chain ~1000 -> ~50 cyc, and 16
// LDS-pipe ops/thread removed. Everything else identical to r19.
#define NPB2 2

__global__ __launch_bounds__(256) void attn_kernel(
    const int* __restrict__ nbr_idx, const int* __restrict__ nbr_mask,
    const float* __restrict__ qf, const __hip_bfloat16* __restrict__ kv,
    float* __restrict__ out, int N)
{
    __shared__ __align__(16) float sl[NPB2][NHEAD][20];  // [head][16 w + pad]

    const int tid = threadIdx.x;
    const int local = tid >> 7; // node within block
    const int t = tid & 127;    // thread within node
    int n = blockIdx.x * NPB2 + local;
    if (n >= N) n = N - 1;  // duplicate work (identical bits), barrier-free safe

    const int hh = t >> 4;   // head (0..7)
    const int kk = t & 15;   // neighbor (scores) / dim (PV)

    const char* kvb = (const char*)kv;
    const unsigned nm1 = (unsigned)(N - 1);

    // idx -> regs: 4x int4 broadcast loads; clamp = single unsigned min
    int idxr[KNBR];
    {
        const int4* ip = reinterpret_cast<const int4*>(nbr_idx + (size_t)n * KNBR);
        #pragma unroll
        for (int m4 = 0; m4 < 4; ++m4) {
            int4 iv = ip[m4];
            idxr[4 * m4 + 0] = (int)min((unsigned)iv.x, nm1);
            idxr[4 * m4 + 1] = (int)min((unsigned)iv.y, nm1);
            idxr[4 * m4 + 2] = (int)min((unsigned)iv.z, nm1);
            idxr[4 * m4 + 3] = (int)min((unsigned)iv.w, nm1);
        }
    }
    const int mymsk = nbr_mask[(size_t)n * KNBR + kk];

    // k direct global->regs: 32B of neighbor kk's k-half, head hh (exec-masked;
    // ~50% lanes skip = BW saved)
    short8 k0 = {0, 0, 0, 0, 0, 0, 0, 0};
    short8 k1 = {0, 0, 0, 0, 0, 0, 0, 0};
    if (mymsk) {
        // byte off = idx*512 + hh*32;  (t&0x70)<<1 == hh*32
        unsigned ko = ((unsigned)idxr[kk] << 9) + (((unsigned)t & 0x70u) << 1);
        k0 = *reinterpret_cast<const short8*>(kvb + ko);
        k1 = *reinterpret_cast<const short8*>(kvb + ko + 16);
    }

    // q -> regs (16-lane broadcast per head, L1-served)
    float qr[HDIM];
    {
        const float4* qp = reinterpret_cast<const float4*>(
            (const char*)qf + (((unsigned)n << 9) + ((unsigned)hh << 6)));
        #pragma unroll
        for (int c4 = 0; c4 < 4; ++c4) {
            float4 qv = qp[c4];
            qr[4 * c4 + 0] = qv.x; qr[4 * c4 + 1] = qv.y;
            qr[4 * c4 + 2] = qv.z; qr[4 * c4 + 3] = qv.w;
        }
    }

    // v direct global->regs: per j the 128 node-threads read 256B contiguous.
    // Issued last; stays in flight across scores+softmax (no barrier drain).
    float vr[KNBR];
    {
        const unsigned vbo = 256u + 2u * (unsigned)t;
        #pragma unroll
        for (int j = 0; j < KNBR; ++j) {
            unsigned u = *reinterpret_cast<const unsigned short*>(
                kvb + ((((unsigned)idxr[j]) << 9) + vbo));
            vr[j] = __uint_as_float(u << 16);
        }
    }

    // scores + DPP rotate-reduce softmax: thread (hh, kk); 16-lane row = head
    {
        const __hip_bfloat162* kp0 = reinterpret_cast<const __hip_bfloat162*>(&k0);
        const __hip_bfloat162* kp1 = reinterpret_cast<const __hip_bfloat162*>(&k1);
        float ax = 0.f, ay = 0.f;   // even/odd paired chains
        #pragma unroll
        for (int d2 = 0; d2 < 4; ++d2) {
            float2 f0 = __bfloat1622float2(kp0[d2]);
            float2 f1 = __bfloat1622float2(kp1[d2]);
            ax = fmaf(qr[2 * d2],     f0.x, ax);
            ay = fmaf(qr[2 * d2 + 1], f0.y, ay);
            ax = fmaf(qr[8 + 2 * d2],     f1.x, ax);
            ay = fmaf(qr[8 + 2 * d2 + 1], f1.y, ay);
        }
        float s = ax + ay;
        if (!mymsk) s = -1e9f;       // masked rows (k regs zero) discarded here
        // rotate-reduce max over the 16-lane row (pure VALU, ~6cyc/step)
        float m = s;
        m = fmaxf(m, dpp_ror<0x121>(m));   // ror 1
        m = fmaxf(m, dpp_ror<0x122>(m));   // ror 2
        m = fmaxf(m, dpp_ror<0x124>(m));   // ror 4
        m = fmaxf(m, dpp_ror<0x128>(m));   // ror 8
        float e = __expf(s - m);
        // rotate-reduce sum
        float d = e;
        d += dpp_ror<0x121>(d);
        d += dpp_ror<0x122>(d);
        d += dpp_ror<0x124>(d);
        d += dpp_ror<0x128>(d);
        sl[local][hh][kk] = e * __builtin_amdgcn_rcpf(d);  // all-masked -> 1/16
    }
    // NO barrier: producer lanes (head hh) and consumer lanes (dims of head hh)
    // are in the same wave; compiler-inserted lgkmcnt orders ds_write->ds_read.

    // PV: w via 4x b128 broadcast; v already in regs -> paired FMA chains
    {
        float ox = 0.f, oy = 0.f;
        const float4* wp = reinterpret_cast<const float4*>(&sl[local][t >> 4][0]);
        #pragma unroll
        for (int m4 = 0; m4 < 4; ++m4) {
            float4 w4 = wp[m4];
            ox = fmaf(w4.x, vr[4 * m4 + 0], ox);
            oy = fmaf(w4.y, vr[4 * m4 + 1], oy);
            ox = fmaf(w4.z, vr[4 * m4 + 2], ox);
            oy = fmaf(w4.w, vr[4 * m4 + 3], oy);
        }
        float* op = reinterpret_cast<float*>(
            (char*)out + (((unsigned)n << 9) + 4u * (unsigned)t));
        *op = ox + oy;  // OUTPUT IS FLOAT32 (verified r6)
    }
}

extern "C" void kernel_launch(void* const* d_in, const int* in_sizes, int n_in,
                              void* d_out, int out_size, void* d_ws, size_t ws_size,
                              hipStream_t stream)
{
    float* out = (float*)d_out;

    bool ok = (n_in == 10);
    int N = ok ? in_sizes[0] / NFEAT : 0;
    ok = ok && N > 0 && in_sizes[0] == N * NFEAT
            && in_sizes[1] == N * KNBR
            && in_sizes[2] == N * KNBR
            && in_sizes[3] == NFEAT * VOCAB * HIDDEN
            && in_sizes[4] == HIDDEN * HIDDEN && in_sizes[5] == HIDDEN
            && in_sizes[6] == HIDDEN * HIDDEN && in_sizes[7] == HIDDEN
            && in_sizes[8] == HIDDEN * HIDDEN && in_sizes[9] == HIDDEN
            && out_size == N * HIDDEN;
    if (!ok) {
        fill_kernel<<<(out_size + 255) / 256, 256, 0, stream>>>(out, out_size, 0.0f);
        return;
    }
    size_t need = (size_t)N * 1024 + 3 * HIDDEN * HIDDEN * sizeof(short);
    if (ws_size < need) {
        fill_kernel<<<(out_size + 255) / 256, 256, 0, stream>>>(out, out_size, 1.0f);
        return;
    }

    const int* X        = (const int*)d_in[0];
    const int* nbr_idx  = (const int*)d_in[1];
    const int* nbr_mask = (const int*)d_in[2];
    const float* emb = (const float*)d_in[3];
    const float* Wq  = (const float*)d_in[4];
    const float* bq  = (const float*)d_in[5];
    const float* Wk  = (const float*)d_in[6];
    const float* bk  = (const float*)d_in[7];
    const float* Wv  = (const float*)d_in[8];
    const float* bv  = (const float*)d_in[9];

    // workspace: qf fp32 [N][128] | kv bf16 [N][256] | Wt bf16 [3][128][128]
    float* qf = (float*)d_ws;
    __hip_bfloat16* kv =
        (__hip_bfloat16*)((char*)d_ws + (size_t)N * HIDDEN * sizeof(float));
    short* Wt = (short*)((char*)d_ws + (size_t)N * 1024);

    wt_kernel<<<12, 256, 0, stream>>>(Wq, Wk, Wv, Wt);
    qkv_kernel<<<(N + MT - 1) / MT, 256, 0, stream>>>(
        X, emb, Wt, bq, bk, bv, qf, kv, N);
    attn_kernel<<<(N + NPB2 - 1) / NPB2, 256, 0, stream>>>(
        nbr_idx, nbr_mask, qf, kv, out, N);
}